// Round 11
// baseline (232.172 us; speedup 1.0000x reference)
//
#include <hip/hip_runtime.h>

#define SIZE_U 1000
#define SIZE_V 1000
#define DIM    128
#define M_EXTRA 16

typedef float f32x4 __attribute__((ext_vector_type(4)));

// Output flat layout (f32 elements):
//   outputs : [0, 2e6)            (1e6 x 2)
//   lnc_rep : [2e6, 130e6)        (1e6 x 128)
//   dis_rep : [130e6, 258e6)      (1e6 x 128)
//   M       : [258e6, 258e6+2048) (16 x 128)
#define OUT_LNC_OFF 2000000L
#define OUT_DIS_OFF 130000000L
#define OUT_M_OFF   258000000L

// R11: score-first phase layout.
//   b in [0, 2000)     : PURE score block (outputs only, 8 MB total writes).
//                        2000 blocks ~= 2048 residency slots -> entire score
//                        phase runs concurrently, retires in ~5-10us.
//   b in [2000, 6000)  : copy blocks, lnc/dis alternating in groups of 8
//                        (XCD parity). Each owns a 256 KB contiguous panel
//                        half (R10 lesson: long contiguous store streams).
//     lnc: pure broadcast store, zero loads in loop (fill-identical).
//     dis: load-once -> store stream, unroll 8.
//   b == 6000          : M copy.
// R5's score-first failure had the 512MB dis_rep store chained inside the
// score reduce loop; here score blocks are pure compute (R7 lesson).
__global__ __launch_bounds__(256) void bilinear_v11_kernel(
    const float* __restrict__ feature,
    const float* __restrict__ weight,
    const float* __restrict__ wc,
    float* __restrict__ out)
{
    const int b = blockIdx.x;
    const int t = threadIdx.x;

    if (b == 6000) {
        const f32x4* src = (const f32x4*)(feature + (size_t)(SIZE_U + SIZE_V) * DIM);
        f32x4* dst = (f32x4*)(out + OUT_M_OFF);
        for (int i = t; i < (M_EXTRA * DIM) / 4; i += 256) dst[i] = src[i];
        return;
    }

    const int c  = t & 31;   // float4 column 0..31
    const int rg = t >> 5;   // row group 0..7
    const f32x4* dis4 = (const f32x4*)(feature + (size_t)SIZE_U * DIM);

    if (b >= 2000) {
        // ---- copy phase: groups of 8 alternate lnc / dis ----
        const int cb   = b - 2000;              // 0..3999
        const int g    = cb >> 3;               // group 0..499
        const int strm = g & 1;                 // 0 = lnc, 1 = dis
        const int id   = (g >> 1) * 8 + (cb & 7);   // 0..1999
        const int u    = id >> 1;
        const int r0   = (id & 1) * 500;
        const int r1   = r0 + 500;
        const size_t rowbase = (size_t)u * SIZE_V;

        if (strm == 0) {
            // pure lnc_rep broadcast: zero loads in loop
            const f32x4 lnc4 = ((const f32x4*)(feature + (size_t)u * DIM))[c];
            f32x4* lr = (f32x4*)(out + OUT_LNC_OFF) + rowbase * (DIM / 4);
            #pragma unroll 8
            for (int r = r0 + rg; r < r1; r += 8)
                lr[r * 32 + c] = lnc4;
        } else {
            // dis_rep: load-once -> store, contiguous 256 KB panel half
            f32x4* dr = (f32x4*)(out + OUT_DIS_OFF) + rowbase * (DIM / 4);
            #pragma unroll 8
            for (int r = r0 + rg; r < r1; r += 8) {
                const int idx = r * 32 + c;
                dr[idx] = dis4[idx];
            }
        }
        return;
    }

    // ---- pure score block: u = b>>1, rows [(b&1)*500, +500) ----
    const int u  = b >> 1;
    const int r0 = (b & 1) * 500;
    const int r1 = r0 + 500;
    const size_t rowbase = (size_t)u * SIZE_V;

    __shared__ float lnc_s[DIM];
    __shared__ float proj_s[2][DIM];
    __shared__ float q_s[2][DIM];

    if (t < DIM) lnc_s[t] = feature[(size_t)u * DIM + t];
    __syncthreads();

    {   // proj[k][e] = sum_d weight[k][d][e] * lnc[d]
        const int k = t >> 7, e = t & 127;
        const float* wk = weight + (size_t)k * DIM * DIM + e;
        float acc = 0.f;
        #pragma unroll 8
        for (int d = 0; d < DIM; ++d)
            acc = fmaf(wk[(size_t)d * DIM], lnc_s[d], acc);
        proj_s[k][e] = acc;
    }
    __syncthreads();

    {   // fold classifier: q[cc][e] = wc[0][cc]*proj0[e] + wc[2+cc]*proj1[e]
        const int cc = t >> 7, e = t & 127;
        q_s[cc][e] = wc[cc] * proj_s[0][e] + wc[2 + cc] * proj_s[1][e];
    }
    __syncthreads();

    const f32x4 q0 = ((const f32x4*)q_s[0])[c];
    const f32x4 q1 = ((const f32x4*)q_s[1])[c];
    float2* outp = (float2*)out;

    #pragma unroll 4
    for (int r = r0 + rg; r < r1; r += 8) {
        const f32x4 dv = dis4[r * 32 + c];
        float t0 = dv.x * q0.x + dv.y * q0.y + dv.z * q0.z + dv.w * q0.w;
        float t1 = dv.x * q1.x + dv.y * q1.y + dv.z * q1.z + dv.w * q1.w;
        #pragma unroll
        for (int off = 16; off; off >>= 1) {
            t0 += __shfl_xor(t0, off);
            t1 += __shfl_xor(t1, off);
        }
        if (c == 0)
            outp[rowbase + r] = make_float2(t0 > 0.f ? t0 : 0.f,
                                            t1 > 0.f ? t1 : 0.f);
    }
}

extern "C" void kernel_launch(void* const* d_in, const int* in_sizes, int n_in,
                              void* d_out, int out_size, void* d_ws, size_t ws_size,
                              hipStream_t stream) {
    const float* feature = (const float*)d_in[0];
    const float* weight  = (const float*)d_in[1];
    const float* wc      = (const float*)d_in[2];
    float* out = (float*)d_out;

    bilinear_v11_kernel<<<6001, 256, 0, stream>>>(feature, weight, wc, out);
}

// Round 12
// 191.057 us; speedup vs baseline: 1.2152x; 1.2152x over previous
//
#include <hip/hip_runtime.h>

#define SIZE_U 1000
#define SIZE_V 1000
#define DIM    128
#define M_EXTRA 16

typedef float f32x4 __attribute__((ext_vector_type(4)));

// Output flat layout (f32 elements):
//   outputs : [0, 2e6)            (1e6 x 2)
//   lnc_rep : [2e6, 130e6)        (1e6 x 128)
//   dis_rep : [130e6, 258e6)      (1e6 x 128)
//   M       : [258e6, 258e6+2048) (16 x 128)
#define OUT_LNC_OFF 2000000L
#define OUT_DIS_OFF 130000000L
#define OUT_M_OFF   258000000L

// R12 = R8 (194us) + ONE change: score results staged in LDS and burst-stored
// as full cache lines. R4-R11 showed scheduling variants don't move the
// 194 -> ~158 gap; the constant across all of them was lane0 8-byte float2
// stores into `outputs` -> partially-dirty 128B lines evicted under 1GB of
// L2 write-thrash -> HBM read-modify-write (~100-250MB extra traffic).
// Now each score block writes its 4KB outputs slice once, fully covered.
//   g = b>>3; role = g&1; j = (g>>1)*8 + (b&7) in [0,2000)
//   u = j>>1; half = j&1 -> rows [half*500, half*500+500)
//   role 0: copy block — phase 1 pure lnc_rep stores, phase 2 dis->dis_rep
//   role 1: score block — unroll-4 shuffle-reduce into LDS, then 4KB burst
//   b == 4000 : M copy
__global__ __launch_bounds__(256) void bilinear_v12_kernel(
    const float* __restrict__ feature,
    const float* __restrict__ weight,
    const float* __restrict__ wc,
    float* __restrict__ out)
{
    const int b = blockIdx.x;
    const int t = threadIdx.x;

    if (b == 4000) {
        const f32x4* src = (const f32x4*)(feature + (size_t)(SIZE_U + SIZE_V) * DIM);
        f32x4* dst = (f32x4*)(out + OUT_M_OFF);
        for (int i = t; i < (M_EXTRA * DIM) / 4; i += 256) dst[i] = src[i];
        return;
    }

    const int g    = b >> 3;
    const int role = g & 1;
    const int j    = (g >> 1) * 8 + (b & 7);
    const int u    = j >> 1;
    const int r0   = (j & 1) * 500;
    const int r1   = r0 + 500;

    const int c  = t & 31;   // float4 column 0..31
    const int rg = t >> 5;   // row group 0..7
    const f32x4* dis4 = (const f32x4*)(feature + (size_t)SIZE_U * DIM);
    const size_t rowbase = (size_t)u * SIZE_V;

    if (role == 0) {
        // ---- phase 1: pure lnc_rep streaming (zero loads) ----
        const f32x4 lnc4 = ((const f32x4*)(feature + (size_t)u * DIM))[c];
        f32x4* lr = (f32x4*)(out + OUT_LNC_OFF) + rowbase * (DIM / 4);
        #pragma unroll 8
        for (int r = r0 + rg; r < r1; r += 8)
            lr[r * 32 + c] = lnc4;

        // ---- phase 2: dis -> dis_rep (load + store, deep unroll) ----
        f32x4* dr = (f32x4*)(out + OUT_DIS_OFF) + rowbase * (DIM / 4);
        #pragma unroll 8
        for (int r = r0 + rg; r < r1; r += 8) {
            const int idx = r * 32 + c;
            dr[idx] = dis4[idx];
        }
    } else {
        // ---- score block ----
        __shared__ float lnc_s[DIM];
        __shared__ float proj_s[2][DIM];
        __shared__ float q_s[2][DIM];
        __shared__ float2 res_s[500];   // 4 KB staging for full-line burst

        if (t < DIM) lnc_s[t] = feature[(size_t)u * DIM + t];
        __syncthreads();

        {   // proj[k][e] = sum_d weight[k][d][e] * lnc[d]
            const int k = t >> 7, e = t & 127;
            const float* wk = weight + (size_t)k * DIM * DIM + e;
            float acc = 0.f;
            #pragma unroll 8
            for (int d = 0; d < DIM; ++d)
                acc = fmaf(wk[(size_t)d * DIM], lnc_s[d], acc);
            proj_s[k][e] = acc;
        }
        __syncthreads();

        {   // fold classifier: q[cc][e] = wc[0][cc]*proj0[e] + wc[2+cc]*proj1[e]
            const int cc = t >> 7, e = t & 127;
            q_s[cc][e] = wc[cc] * proj_s[0][e] + wc[2 + cc] * proj_s[1][e];
        }
        __syncthreads();

        const f32x4 q0 = ((const f32x4*)q_s[0])[c];
        const f32x4 q1 = ((const f32x4*)q_s[1])[c];

        #pragma unroll 4
        for (int r = r0 + rg; r < r1; r += 8) {
            const f32x4 dv = dis4[r * 32 + c];
            float t0 = dv.x * q0.x + dv.y * q0.y + dv.z * q0.z + dv.w * q0.w;
            float t1 = dv.x * q1.x + dv.y * q1.y + dv.z * q1.z + dv.w * q1.w;
            #pragma unroll
            for (int off = 16; off; off >>= 1) {
                t0 += __shfl_xor(t0, off);
                t1 += __shfl_xor(t1, off);
            }
            if (c == 0)
                res_s[r - r0] = make_float2(t0 > 0.f ? t0 : 0.f,
                                            t1 > 0.f ? t1 : 0.f);
        }
        __syncthreads();

        // burst: 500 float2 = 250 f32x4, contiguous + 16B-aligned
        f32x4* ob = (f32x4*)(out + (size_t)u * (2 * SIZE_V) + (size_t)r0 * 2);
        if (t < 250) ob[t] = ((const f32x4*)res_s)[t];
    }
}

extern "C" void kernel_launch(void* const* d_in, const int* in_sizes, int n_in,
                              void* d_out, int out_size, void* d_ws, size_t ws_size,
                              hipStream_t stream) {
    const float* feature = (const float*)d_in[0];
    const float* weight  = (const float*)d_in[1];
    const float* wc      = (const float*)d_in[2];
    float* out = (float*)d_out;

    bilinear_v12_kernel<<<4001, 256, 0, stream>>>(feature, weight, wc, out);
}